// Round 3
// baseline (443.956 us; speedup 1.0000x reference)
//
#include <hip/hip_runtime.h>

#define NSEG 2048
#define EPS 1e-6f
#define BLK 1024
#define RPT 10          // float4 per thread per segment buffer -> capacity 640 rows/seg
                        // (seg sizes ~ Binomial(1e6,1/2048): mean 488, sd 22; 640 = +6.9 sigma,
                        //  validated: round-2 kernel passed with this exact cap)
#define SPB 8           // segments per block -> grid = NSEG/SPB = 256 = one block per CU
#define GRID (NSEG / SPB)

typedef float nfloat4 __attribute__((ext_vector_type(4)));  // native vec for nt store

// Build starts[0..NSEG]: starts[b] = first row index i with seg[i] >= b.
// seg is sorted, so every entry is written exactly once (empty segs included).
__global__ void starts_k(const int* __restrict__ seg, int* __restrict__ starts, int n) {
    int i = blockIdx.x * blockDim.x + threadIdx.x;
    if (i >= n) return;
    int s = seg[i];
    int prev = (i == 0) ? -1 : seg[i - 1];
    for (int k = prev + 1; k <= s; ++k) starts[k] = i;
    if (i == n - 1) {
        for (int k = s + 1; k <= NSEG; ++k) starts[k] = n;
    }
}

__device__ __forceinline__ void wave_reduce(float& mn, float& mx) {
#pragma unroll
    for (int off = 32; off; off >>= 1) {
        mn = fminf(mn, __shfl_xor(mn, off));
        mx = fmaxf(mx, __shfl_xor(mx, off));
    }
}

__device__ __forceinline__ void min4max4(const float4& v, float& mn, float& mx) {
    mn = fminf(mn, fminf(fminf(v.x, v.y), fminf(v.z, v.w)));
    mx = fmaxf(mx, fmaxf(fmaxf(v.x, v.y), fmaxf(v.z, v.w)));
}

// Persistent pipelined kernel: 256 blocks (exactly one per CU, enforced by the
// 16-wave/128-VGPR footprint), 8 contiguous segments per block, register
// double-buffered: reduce(k) -> barrier -> issue loads(k+1) -> NT-store(k).
// Loads of k+1 drain concurrently with stores of k -> mixed R/W saturation;
// the only cold bubble is the one prologue load per block.
__global__ __launch_bounds__(BLK, 4) void norm_seg(const float4* __restrict__ x4,
                                                   const int* __restrict__ starts,
                                                   nfloat4* __restrict__ out4) {
    const int t = threadIdx.x;
    __shared__ float2 red[2][BLK / 64];  // parity-buffered: no 2nd barrier, no clobber race

    int st[SPB + 1];
#pragma unroll
    for (int j = 0; j <= SPB; ++j) st[j] = starts[blockIdx.x * SPB + j];  // uniform -> s_loads

    bool big = false;
#pragma unroll
    for (int j = 0; j < SPB; ++j) big |= (st[j + 1] - st[j]) > BLK * RPT / 16;

    if (!big) {
        // ---------------- pipelined register-resident path (always, in practice) ----------------
        float4 vb[2][RPT];

        {   // prologue: load segment 0 into buffer 0
            const long f0 = (long)st[0] * 16;
            const int n0 = (st[1] - st[0]) * 16;
#pragma unroll
            for (int i = 0; i < RPT; ++i) {
                int idx = i * BLK + t;
                if (idx < n0) vb[0][i] = x4[f0 + idx];
            }
        }

#pragma unroll
        for (int k = 0; k < SPB; ++k) {        // fully unrolled: k, cur, nxt compile-time
            const int cur = k & 1, nxt = cur ^ 1;
            const long fk = (long)st[k] * 16;
            const int nk = (st[k + 1] - st[k]) * 16;

            // reduce current segment (consumes loads as they return)
            float lmin = INFINITY, lmax = -INFINITY;
#pragma unroll
            for (int i = 0; i < RPT; ++i) {
                int idx = i * BLK + t;
                if (idx < nk) min4max4(vb[cur][i], lmin, lmax);
            }
            wave_reduce(lmin, lmax);
            if ((t & 63) == 0) red[cur][t >> 6] = make_float2(lmin, lmax);
            __syncthreads();
            float mn = INFINITY, mx = -INFINITY;
#pragma unroll
            for (int w = 0; w < BLK / 64; ++w) {
                mn = fminf(mn, red[cur][w].x);
                mx = fmaxf(mx, red[cur][w].y);
            }
            const float sc = 1.0f / (mx - mn + EPS);  // identical numerics to passing kernel

            // issue NEXT segment's loads before storing: reads fly under the store drain
            if (k + 1 < SPB) {
                const long fn = (long)st[k + 1] * 16;
                const int nn = (st[k + 2] - st[k + 1]) * 16;
#pragma unroll
                for (int i = 0; i < RPT; ++i) {
                    int idx = i * BLK + t;
                    if (idx < nn) vb[nxt][i] = x4[fn + idx];
                }
            }

            // store current segment from registers
#pragma unroll
            for (int i = 0; i < RPT; ++i) {
                int idx = i * BLK + t;
                if (idx < nk) {
                    nfloat4 o;
                    o.x = (vb[cur][i].x - mn) * sc;
                    o.y = (vb[cur][i].y - mn) * sc;
                    o.z = (vb[cur][i].z - mn) * sc;
                    o.w = (vb[cur][i].w - mn) * sc;
                    __builtin_nontemporal_store(o, &out4[fk + idx]);
                }
            }
        }
    } else {
        // ---------------- fallback: some oversized segment, chunked two-pass ----------------
        for (int k = 0; k < SPB; ++k) {
            const long fk = (long)st[k] * 16;
            const int nk = (st[k + 1] - st[k]) * 16;
            if (nk <= 0) { __syncthreads(); __syncthreads(); continue; }
            float lmin = INFINITY, lmax = -INFINITY;
            for (int base = 0; base < nk; base += BLK) {
                int idx = base + t;
                if (idx < nk) {
                    float4 v = x4[fk + idx];
                    min4max4(v, lmin, lmax);
                }
            }
            wave_reduce(lmin, lmax);
            if ((t & 63) == 0) red[0][t >> 6] = make_float2(lmin, lmax);
            __syncthreads();
            float mn = INFINITY, mx = -INFINITY;
#pragma unroll
            for (int w = 0; w < BLK / 64; ++w) {
                mn = fminf(mn, red[0][w].x);
                mx = fmaxf(mx, red[0][w].y);
            }
            const float sc = 1.0f / (mx - mn + EPS);
            for (int base = 0; base < nk; base += BLK) {
                int idx = base + t;
                if (idx < nk) {
                    float4 v = x4[fk + idx];  // re-read: L2-hot for sane sizes
                    nfloat4 o;
                    o.x = (v.x - mn) * sc;
                    o.y = (v.y - mn) * sc;
                    o.z = (v.z - mn) * sc;
                    o.w = (v.w - mn) * sc;
                    __builtin_nontemporal_store(o, &out4[fk + idx]);
                }
            }
            __syncthreads();  // protect red[0] reuse across segments
        }
    }
}

extern "C" void kernel_launch(void* const* d_in, const int* in_sizes, int n_in,
                              void* d_out, int out_size, void* d_ws, size_t ws_size,
                              hipStream_t stream) {
    const float4* x4 = (const float4*)d_in[0];
    const int* seg = (const int*)d_in[1];
    nfloat4* out4 = (nfloat4*)d_out;
    const int nrows = in_sizes[1];  // N = 1,000,000

    int* starts = (int*)d_ws;  // [NSEG + 1], fully rewritten every call

    starts_k<<<(nrows + 255) / 256, 256, 0, stream>>>(seg, starts, nrows);
    norm_seg<<<GRID, BLK, 0, stream>>>(x4, starts, out4);
}